// Round 1
// baseline (1107.741 us; speedup 1.0000x reference)
//
#include <hip/hip_runtime.h>
#include <stdint.h>

#define D_IN 1280

typedef __attribute__((ext_vector_type(8))) short s16x8;
typedef __attribute__((ext_vector_type(4))) float f32x4;

__device__ __forceinline__ unsigned short f2bf(float f) {
  union { float f; unsigned u; } v;
  v.f = f;
  unsigned u = v.u;
  return (unsigned short)((u + 0x7fffu + ((u >> 16) & 1u)) >> 16);  // RNE
}

__device__ __forceinline__ void gload_lds16(const void* g, void* l) {
  __builtin_amdgcn_global_load_lds(
      (const __attribute__((address_space(1))) void*)g,
      (__attribute__((address_space(3))) void*)l, 16, 0, 0);
}

// ---------------- Cayley: Q = (I - S) @ inv(I + S), S = 0.5(A - A^T) -------
// One block per matrix (n = 4, 8, 40). Gauss-Jordan with partial pivoting in LDS.
__global__ void cayley_kernel(const float* __restrict__ A1,
                              const float* __restrict__ A2,
                              const float* __restrict__ A3,
                              float* __restrict__ qws) {
  const int which = blockIdx.x;
  const float* __restrict__ A = which == 0 ? A1 : (which == 1 ? A2 : A3);
  float* __restrict__ Q = which == 0 ? qws : (which == 1 ? qws + 16 : qws + 80);
  const int n = which == 0 ? 4 : (which == 1 ? 8 : 40);
  const int t = threadIdx.x;

  __shared__ float aug[40][80];
  __shared__ float Nm[40][40];
  __shared__ float fac[40];
  __shared__ int piv;

  for (int idx = t; idx < n * n; idx += 256) {
    int i = idx / n, j = idx % n;
    float s = 0.5f * (A[i * n + j] - A[j * n + i]);
    float eye = (i == j) ? 1.0f : 0.0f;
    aug[i][j] = eye + s;        // M = I + S
    aug[i][n + j] = eye;        // augmented identity
    Nm[i][j] = eye - s;         // N = I - S
  }
  __syncthreads();

  for (int p = 0; p < n; ++p) {
    if (t == 0) {
      int best = p;
      float bv = fabsf(aug[p][p]);
      for (int i = p + 1; i < n; ++i) {
        float v = fabsf(aug[i][p]);
        if (v > bv) { bv = v; best = i; }
      }
      piv = best;
    }
    __syncthreads();
    const int pr = piv;
    if (pr != p) {
      for (int j = t; j < 2 * n; j += 256) {
        float tmp = aug[p][j];
        aug[p][j] = aug[pr][j];
        aug[pr][j] = tmp;
      }
    }
    __syncthreads();
    const float d = aug[p][p];   // everyone reads the pivot...
    __syncthreads();             // ...before anyone scales the row
    const float inv = 1.0f / d;
    for (int j = t; j < 2 * n; j += 256) aug[p][j] *= inv;
    __syncthreads();
    for (int i = t; i < n; i += 256) fac[i] = (i == p) ? 0.0f : aug[i][p];
    __syncthreads();
    for (int idx = t; idx < n * 2 * n; idx += 256) {
      int i = idx / (2 * n), j = idx % (2 * n);
      if (i != p) aug[i][j] -= fac[i] * aug[p][j];
    }
    __syncthreads();
  }

  // Q = Nm @ Minv  (Minv = aug[:, n:2n])
  for (int idx = t; idx < n * n; idx += 256) {
    int i = idx / n, j = idx % n;
    float acc = 0.0f;
    for (int k = 0; k < n; ++k) acc += Nm[i][k] * aug[k][n + j];
    Q[i * n + j] = acc;
  }
}

// ---------------- filt[o,i] = sum_j W[o,j] * R[i,j], R = q1 (x) q2 (x) q3 ---
// i = i1*320 + i2*40 + i3. Per-thread factored reduction, q3 transposed in LDS
// for conflict-free reads. Output bf16.
__global__ void filt_kernel(const float* __restrict__ W,
                            const float* __restrict__ qws,
                            unsigned short* __restrict__ filt) {
  __shared__ float q1s[16];
  __shared__ float q2s[64];
  __shared__ float q3t[40][40];
  const int t = threadIdx.x;
  if (t < 16) q1s[t] = qws[t];
  if (t < 64) q2s[t] = qws[16 + t];
  for (int k = t; k < 1600; k += 256) {
    int i = k / 40, j = k % 40;
    q3t[j][i] = qws[80 + k];
  }
  __syncthreads();

  const int idx = blockIdx.x * 256 + t;
  const int o = idx / D_IN;
  const int i = idx % D_IN;
  const int i1 = i / 320;
  const int i2 = (i / 40) & 7;
  const int i3 = i % 40;
  const float* __restrict__ wrow = W + (size_t)o * D_IN;

  float acc = 0.0f;
  for (int j1 = 0; j1 < 4; ++j1) {
    const float a1 = q1s[i1 * 4 + j1];
    for (int j2 = 0; j2 < 8; ++j2) {
      const float a12 = a1 * q2s[i2 * 8 + j2];
      const float* __restrict__ w = wrow + j1 * 320 + j2 * 40;
      float s = 0.0f;
#pragma unroll
      for (int j3 = 0; j3 < 40; ++j3) s += w[j3] * q3t[j3][i3];
      acc += a12 * s;
    }
  }
  filt[idx] = f2bf(acc);
}

// ---------------- main GEMM: out[m,n] = sum_k x[m,k] * filt[n,k] ------------
// M=32768, N=1280, K=1280. 128x128 tile, BK=32, 4 waves (each 64x64 as 4x4
// 16x16 fragments), bf16 MFMA. A: fp32 reg-staged + cvt; B: global_load_lds.
__global__ __launch_bounds__(256) void gemm_kernel(const float* __restrict__ x,
                                                   const unsigned short* __restrict__ filt,
                                                   float* __restrict__ out) {
  __shared__ short As[128][32];
  __shared__ short Bs[128][32];

  const int t = threadIdx.x;
  const int lane = t & 63;
  const int wave = t >> 6;
  const int wr = wave >> 1;
  const int wc = wave & 1;

  const int nwg = gridDim.x;                      // 2560, % 8 == 0
  const int bid = blockIdx.x;
  const int wg = (bid & 7) * (nwg >> 3) + (bid >> 3);  // bijective XCD swizzle
  const int mt = wg / 10;
  const int nt = wg % 10;
  const int mbase = mt * 128;
  const int nbase = nt * 128;

  f32x4 acc[4][4];
#pragma unroll
  for (int m = 0; m < 4; ++m)
#pragma unroll
    for (int n = 0; n < 4; ++n) acc[m][n] = 0.0f;

  // A staging: thread t loads 16 fp32 of row (t>>1), cols (t&1)*16..+16
  const int ar = t >> 1;
  const int ac = (t & 1) << 4;
  const float* __restrict__ asrc = x + (size_t)(mbase + ar) * D_IN + ac;

  // B staging via global_load_lds: thread t covers LDS bytes t*16 (+4096)
  const int br = t >> 2;
  const int bc = (t & 3) << 3;
  const unsigned short* __restrict__ bsrc0 = filt + (size_t)(nbase + br) * D_IN + bc;
  const unsigned short* __restrict__ bsrc1 = filt + (size_t)(nbase + br + 64) * D_IN + bc;
  short* bdst0 = &Bs[br][bc];
  short* bdst1 = &Bs[br + 64][bc];

  const int lr = lane & 15;
  const int lk = (lane >> 4) << 3;

  for (int kt = 0; kt < D_IN; kt += 32) {
    gload_lds16(bsrc0 + kt, bdst0);
    gload_lds16(bsrc1 + kt, bdst1);

    const float* src = asrc + kt;
    float4 f0 = *(const float4*)(src + 0);
    float4 f1 = *(const float4*)(src + 4);
    float4 f2 = *(const float4*)(src + 8);
    float4 f3 = *(const float4*)(src + 12);
    s16x8 p0, p1;
    p0[0] = (short)f2bf(f0.x); p0[1] = (short)f2bf(f0.y);
    p0[2] = (short)f2bf(f0.z); p0[3] = (short)f2bf(f0.w);
    p0[4] = (short)f2bf(f1.x); p0[5] = (short)f2bf(f1.y);
    p0[6] = (short)f2bf(f1.z); p0[7] = (short)f2bf(f1.w);
    p1[0] = (short)f2bf(f2.x); p1[1] = (short)f2bf(f2.y);
    p1[2] = (short)f2bf(f2.z); p1[3] = (short)f2bf(f2.w);
    p1[4] = (short)f2bf(f3.x); p1[5] = (short)f2bf(f3.y);
    p1[6] = (short)f2bf(f3.z); p1[7] = (short)f2bf(f3.w);
    *(s16x8*)&As[ar][ac] = p0;
    *(s16x8*)&As[ar][ac + 8] = p1;

    __syncthreads();

    s16x8 a[4], b[4];
#pragma unroll
    for (int m = 0; m < 4; ++m)
      a[m] = *(const s16x8*)&As[wr * 64 + m * 16 + lr][lk];
#pragma unroll
    for (int n = 0; n < 4; ++n)
      b[n] = *(const s16x8*)&Bs[wc * 64 + n * 16 + lr][lk];
#pragma unroll
    for (int m = 0; m < 4; ++m)
#pragma unroll
      for (int n = 0; n < 4; ++n)
        acc[m][n] = __builtin_amdgcn_mfma_f32_16x16x32_bf16(a[m], b[n], acc[m][n], 0, 0, 0);

    __syncthreads();
  }

  // C/D layout: col = lane&15, row = (lane>>4)*4 + reg
  const int orow = (lane >> 4) << 2;
  const int ocol = lane & 15;
#pragma unroll
  for (int m = 0; m < 4; ++m) {
#pragma unroll
    for (int r = 0; r < 4; ++r) {
      float* cp = out + (size_t)(mbase + wr * 64 + m * 16 + orow + r) * D_IN +
                  nbase + wc * 64 + ocol;
#pragma unroll
      for (int n = 0; n < 4; ++n) cp[n * 16] = acc[m][n][r];
    }
  }
}

extern "C" void kernel_launch(void* const* d_in, const int* in_sizes, int n_in,
                              void* d_out, int out_size, void* d_ws, size_t ws_size,
                              hipStream_t stream) {
  (void)in_sizes; (void)n_in; (void)out_size; (void)ws_size;
  const float* x = (const float*)d_in[0];
  const float* k1 = (const float*)d_in[1];
  const float* k2 = (const float*)d_in[2];
  const float* k3 = (const float*)d_in[3];
  const float* W = (const float*)d_in[4];
  float* out = (float*)d_out;

  // ws layout: [0,8192) q1|q2|q3 (f32: 16 + 64 + 1600), [8192, +3.3MB) filt bf16
  float* qws = (float*)d_ws;
  unsigned short* filt = (unsigned short*)((char*)d_ws + 8192);

  cayley_kernel<<<3, 256, 0, stream>>>(k1, k2, k3, qws);
  filt_kernel<<<6400, 256, 0, stream>>>(W, qws, filt);
  gemm_kernel<<<2560, 256, 0, stream>>>(x, filt, out);
}

// Round 2
// 360.549 us; speedup vs baseline: 3.0724x; 3.0724x over previous
//
#include <hip/hip_runtime.h>
#include <stdint.h>

#define D_IN 1280

typedef __attribute__((ext_vector_type(8))) short s16x8;
typedef __attribute__((ext_vector_type(4))) float f32x4;

__device__ __forceinline__ unsigned short f2bf(float f) {
  union { float f; unsigned u; } v;
  v.f = f;
  unsigned u = v.u;
  return (unsigned short)((u + 0x7fffu + ((u >> 16) & 1u)) >> 16);  // RNE
}

__device__ __forceinline__ void gload_lds16(const void* g, void* l) {
  __builtin_amdgcn_global_load_lds(
      (const __attribute__((address_space(1))) void*)g,
      (__attribute__((address_space(3))) void*)l, 16, 0, 0);
}

// ---------------- Cayley: Q = (I - S) @ inv(I + S), S = 0.5(A - A^T) -------
// One block per matrix (n = 4, 8, 40). Gauss-Jordan with partial pivoting in LDS.
__global__ void cayley_kernel(const float* __restrict__ A1,
                              const float* __restrict__ A2,
                              const float* __restrict__ A3,
                              float* __restrict__ qws) {
  const int which = blockIdx.x;
  const float* __restrict__ A = which == 0 ? A1 : (which == 1 ? A2 : A3);
  float* __restrict__ Q = which == 0 ? qws : (which == 1 ? qws + 16 : qws + 80);
  const int n = which == 0 ? 4 : (which == 1 ? 8 : 40);
  const int t = threadIdx.x;

  __shared__ float aug[40][80];
  __shared__ float Nm[40][40];
  __shared__ float fac[40];
  __shared__ int piv;

  for (int idx = t; idx < n * n; idx += 256) {
    int i = idx / n, j = idx % n;
    float s = 0.5f * (A[i * n + j] - A[j * n + i]);
    float eye = (i == j) ? 1.0f : 0.0f;
    aug[i][j] = eye + s;        // M = I + S
    aug[i][n + j] = eye;        // augmented identity
    Nm[i][j] = eye - s;         // N = I - S
  }
  __syncthreads();

  for (int p = 0; p < n; ++p) {
    if (t == 0) {
      int best = p;
      float bv = fabsf(aug[p][p]);
      for (int i = p + 1; i < n; ++i) {
        float v = fabsf(aug[i][p]);
        if (v > bv) { bv = v; best = i; }
      }
      piv = best;
    }
    __syncthreads();
    const int pr = piv;
    if (pr != p) {
      for (int j = t; j < 2 * n; j += 256) {
        float tmp = aug[p][j];
        aug[p][j] = aug[pr][j];
        aug[pr][j] = tmp;
      }
    }
    __syncthreads();
    const float d = aug[p][p];   // everyone reads the pivot...
    __syncthreads();             // ...before anyone scales the row
    const float inv = 1.0f / d;
    for (int j = t; j < 2 * n; j += 256) aug[p][j] *= inv;
    __syncthreads();
    for (int i = t; i < n; i += 256) fac[i] = (i == p) ? 0.0f : aug[i][p];
    __syncthreads();
    for (int idx = t; idx < n * 2 * n; idx += 256) {
      int i = idx / (2 * n), j = idx % (2 * n);
      if (i != p) aug[i][j] -= fac[i] * aug[p][j];
    }
    __syncthreads();
  }

  // Q = Nm @ Minv  (Minv = aug[:, n:2n])
  for (int idx = t; idx < n * n; idx += 256) {
    int i = idx / n, j = idx % n;
    float acc = 0.0f;
    for (int k = 0; k < n; ++k) acc += Nm[i][k] * aug[k][n + j];
    Q[i * n + j] = acc;
  }
}

// ---------------- filt[o,:] = (q1 (x) q2 (x) q3) @ w_o, staged in LDS ------
// Per o-row: reshape w to [4][8][40]; contract q3 (40 MACs), q2 (8), q1 (4).
// ~66.5K MACs/row instead of 1.64M. One block per o.
__global__ void filt_kernel(const float* __restrict__ W,
                            const float* __restrict__ qws,
                            unsigned short* __restrict__ filt) {
  __shared__ float q1s[16];
  __shared__ float q2s[64];
  __shared__ float q3t[40][40];
  __shared__ float w[D_IN];
  __shared__ float t1[D_IN];
  __shared__ float t2[D_IN];
  const int t = threadIdx.x;
  const int o = blockIdx.x;

  if (t < 16) q1s[t] = qws[t];
  if (t < 64) q2s[t] = qws[16 + t];
  for (int k = t; k < 1600; k += 256) q3t[k % 40][k / 40] = qws[80 + k];  // q3t[j3][i3]
  const float4* __restrict__ wsrc = (const float4*)(W + (size_t)o * D_IN);
  for (int k = t; k < 320; k += 256) ((float4*)w)[k] = wsrc[k];
  __syncthreads();

  // step A: t1[j1*320 + j2*40 + i3] = sum_j3 w[j1*320 + j2*40 + j3] * q3[i3][j3]
  for (int e = t; e < D_IN; e += 256) {
    const int i3 = e % 40;
    const int b = e - i3;  // j1*320 + j2*40
    float s = 0.0f;
#pragma unroll
    for (int j3 = 0; j3 < 40; ++j3) s += w[b + j3] * q3t[j3][i3];
    t1[e] = s;
  }
  __syncthreads();

  // step B: t2[j1*320 + i2*40 + i3] = sum_j2 q2[i2*8 + j2] * t1[j1*320 + j2*40 + i3]
  for (int e = t; e < D_IN; e += 256) {
    const int i3 = e % 40;
    const int i2 = (e / 40) & 7;
    const int j1 = e / 320;
    float s = 0.0f;
#pragma unroll
    for (int j2 = 0; j2 < 8; ++j2) s += q2s[i2 * 8 + j2] * t1[j1 * 320 + j2 * 40 + i3];
    t2[e] = s;
  }
  __syncthreads();

  // step C: filt[o, i1*320 + i2*40 + i3] = sum_j1 q1[i1*4 + j1] * t2[j1*320 + i2*40 + i3]
  for (int e = t; e < D_IN; e += 256) {
    const int lo = e % 320;  // i2*40 + i3
    const int i1 = e / 320;
    float s = 0.0f;
#pragma unroll
    for (int j1 = 0; j1 < 4; ++j1) s += q1s[i1 * 4 + j1] * t2[j1 * 320 + lo];
    filt[(size_t)o * D_IN + e] = f2bf(s);
  }
}

// ---------------- main GEMM: out[m,n] = sum_k x[m,k] * filt[n,k] ------------
// M=32768, N=1280, K=1280. 128x128 tile, BK=32, 4 waves (each 64x64 as 4x4
// 16x16 fragments), bf16 MFMA. A: fp32 reg-staged + cvt; B: global_load_lds.
__global__ __launch_bounds__(256) void gemm_kernel(const float* __restrict__ x,
                                                   const unsigned short* __restrict__ filt,
                                                   float* __restrict__ out) {
  __shared__ short As[128][32];
  __shared__ short Bs[128][32];

  const int t = threadIdx.x;
  const int lane = t & 63;
  const int wave = t >> 6;
  const int wr = wave >> 1;
  const int wc = wave & 1;

  const int nwg = gridDim.x;                      // 2560, % 8 == 0
  const int bid = blockIdx.x;
  const int wg = (bid & 7) * (nwg >> 3) + (bid >> 3);  // bijective XCD swizzle
  const int mt = wg / 10;
  const int nt = wg % 10;
  const int mbase = mt * 128;
  const int nbase = nt * 128;

  f32x4 acc[4][4];
#pragma unroll
  for (int m = 0; m < 4; ++m)
#pragma unroll
    for (int n = 0; n < 4; ++n) acc[m][n] = 0.0f;

  // A staging: thread t loads 16 fp32 of row (t>>1), cols (t&1)*16..+16
  const int ar = t >> 1;
  const int ac = (t & 1) << 4;
  const float* __restrict__ asrc = x + (size_t)(mbase + ar) * D_IN + ac;

  // B staging via global_load_lds: thread t covers LDS bytes t*16 (+4096)
  const int br = t >> 2;
  const int bc = (t & 3) << 3;
  const unsigned short* __restrict__ bsrc0 = filt + (size_t)(nbase + br) * D_IN + bc;
  const unsigned short* __restrict__ bsrc1 = filt + (size_t)(nbase + br + 64) * D_IN + bc;
  short* bdst0 = &Bs[br][bc];
  short* bdst1 = &Bs[br + 64][bc];

  const int lr = lane & 15;
  const int lk = (lane >> 4) << 3;

  for (int kt = 0; kt < D_IN; kt += 32) {
    gload_lds16(bsrc0 + kt, bdst0);
    gload_lds16(bsrc1 + kt, bdst1);

    const float* src = asrc + kt;
    float4 f0 = *(const float4*)(src + 0);
    float4 f1 = *(const float4*)(src + 4);
    float4 f2 = *(const float4*)(src + 8);
    float4 f3 = *(const float4*)(src + 12);
    s16x8 p0, p1;
    p0[0] = (short)f2bf(f0.x); p0[1] = (short)f2bf(f0.y);
    p0[2] = (short)f2bf(f0.z); p0[3] = (short)f2bf(f0.w);
    p0[4] = (short)f2bf(f1.x); p0[5] = (short)f2bf(f1.y);
    p0[6] = (short)f2bf(f1.z); p0[7] = (short)f2bf(f1.w);
    p1[0] = (short)f2bf(f2.x); p1[1] = (short)f2bf(f2.y);
    p1[2] = (short)f2bf(f2.z); p1[3] = (short)f2bf(f2.w);
    p1[4] = (short)f2bf(f3.x); p1[5] = (short)f2bf(f3.y);
    p1[6] = (short)f2bf(f3.z); p1[7] = (short)f2bf(f3.w);
    *(s16x8*)&As[ar][ac] = p0;
    *(s16x8*)&As[ar][ac + 8] = p1;

    __syncthreads();

    s16x8 a[4], b[4];
#pragma unroll
    for (int m = 0; m < 4; ++m)
      a[m] = *(const s16x8*)&As[wr * 64 + m * 16 + lr][lk];
#pragma unroll
    for (int n = 0; n < 4; ++n)
      b[n] = *(const s16x8*)&Bs[wc * 64 + n * 16 + lr][lk];
#pragma unroll
    for (int m = 0; m < 4; ++m)
#pragma unroll
      for (int n = 0; n < 4; ++n)
        acc[m][n] = __builtin_amdgcn_mfma_f32_16x16x32_bf16(a[m], b[n], acc[m][n], 0, 0, 0);

    __syncthreads();
  }

  // C/D layout: col = lane&15, row = (lane>>4)*4 + reg
  const int orow = (lane >> 4) << 2;
  const int ocol = lane & 15;
#pragma unroll
  for (int m = 0; m < 4; ++m) {
#pragma unroll
    for (int r = 0; r < 4; ++r) {
      float* cp = out + (size_t)(mbase + wr * 64 + m * 16 + orow + r) * D_IN +
                  nbase + wc * 64 + ocol;
#pragma unroll
      for (int n = 0; n < 4; ++n) cp[n * 16] = acc[m][n][r];
    }
  }
}

extern "C" void kernel_launch(void* const* d_in, const int* in_sizes, int n_in,
                              void* d_out, int out_size, void* d_ws, size_t ws_size,
                              hipStream_t stream) {
  (void)in_sizes; (void)n_in; (void)out_size; (void)ws_size;
  const float* x = (const float*)d_in[0];
  const float* k1 = (const float*)d_in[1];
  const float* k2 = (const float*)d_in[2];
  const float* k3 = (const float*)d_in[3];
  const float* W = (const float*)d_in[4];
  float* out = (float*)d_out;

  // ws layout: [0,8192) q1|q2|q3 (f32: 16 + 64 + 1600), [8192, +3.3MB) filt bf16
  float* qws = (float*)d_ws;
  unsigned short* filt = (unsigned short*)((char*)d_ws + 8192);

  cayley_kernel<<<3, 256, 0, stream>>>(k1, k2, k3, qws);
  filt_kernel<<<D_IN, 256, 0, stream>>>(W, qws, filt);
  gemm_kernel<<<2560, 256, 0, stream>>>(x, filt, out);
}